// Round 5
// baseline (91.030 us; speedup 1.0000x reference)
//
#include <hip/hip_runtime.h>

// RoIAlign-3D: x[2,256,16,64,64] f32, rois[128,5] -> out[128,256,16,7,7] f32
// R5: G=4 t-plane-interleaved LDS (v4f lds[64][64], 64KB exact). One lane
// computes 4 outputs (4 planes) per (roi,ph,pw): 3 rows x 1 ds_read_b128*3,
// metadata once per 4 outputs, in-register (no tables). Persistent blocks:
// grid=512 (2/CU), loop 4 t-sets, reg-staged prefetch (T14) hides HBM latency.
// Boundary: window base clamped (yb/xb <= 61) + weight shift, so no pads.

typedef float v4f __attribute__((ext_vector_type(4)));

__global__ __launch_bounds__(128) void pooler_pre(const float* __restrict__ rois,
                                                  float* __restrict__ wf,
                                                  int* __restrict__ wi) {
    __shared__ int sb[128];
    __shared__ int slot[128];
    const int k = threadIdx.x;
    sb[k] = (int)rois[5 * k];
    __syncthreads();
    if (k == 0) {
        int c0 = 0, c1 = 0;
        for (int j = 0; j < 128; ++j) {
            if (sb[j] == 0) slot[j] = c0++;
            else            slot[j] = 128 + c1++;
        }
        wi[0] = c0; wi[1] = c1;
    }
    __syncthreads();
    float x1 = rois[5 * k + 1] * 0.25f, y1 = rois[5 * k + 2] * 0.25f;
    float x2 = rois[5 * k + 3] * 0.25f, y2 = rois[5 * k + 4] * 0.25f;
    int e = 16 + slot[k] * 8;          // slot encodes image (+128 for b=1)
    wf[e + 0] = x1;
    wf[e + 1] = y1;
    wf[e + 2] = fmaxf(x2 - x1, 1.0f) * (1.0f / 14.0f);
    wf[e + 3] = fmaxf(y2 - y1, 1.0f) * (1.0f / 14.0f);
    wi[e + 4] = k;
}

__global__ __launch_bounds__(512, 4) void pooler_main(const float* __restrict__ x,
                                                      const float* __restrict__ wf,
                                                      const int* __restrict__ wi,
                                                      float* __restrict__ out) {
    __shared__ v4f lds4[4096];         // [y][x] -> 4 t-planes interleaved; 64KB
    const int tid = threadIdx.x;
    const int bid = blockIdx.x;
    const int b = bid >> 8, c = bid & 255;
    const float* base = x + ((size_t)(b * 256 + c) << 16);   // 16 planes * 4096
    const int nroi  = wi[b];
    const int ntask = nroi * 7;

    // Prologue: load t-set 0 into registers (4 scattered-plane words per pos,
    // coalesced across lanes per (j,g) instruction).
    v4f buf[8];
    #pragma unroll
    for (int j = 0; j < 8; ++j) {
        int p = tid + j * 512;
        #pragma unroll
        for (int g = 0; g < 4; ++g) buf[j][g] = base[(g << 12) + p];
    }

    for (int tset = 0; tset < 4; ++tset) {
        __syncthreads();               // prior compute done reading LDS
        #pragma unroll
        for (int j = 0; j < 8; ++j) lds4[tid + j * 512] = buf[j];  // linear b128, conflict-free
        __syncthreads();
        if (tset < 3) {                // issue next t-set loads; land under compute
            const float* nb = base + ((size_t)(tset + 1) << 14);
            #pragma unroll
            for (int j = 0; j < 8; ++j) {
                int p = tid + j * 512;
                #pragma unroll
                for (int g = 0; g < 4; ++g) buf[j][g] = nb[(g << 12) + p];
            }
        }

        for (int task = tid; task < ntask; task += 512) {
            int r = task / 7, ph = task - r * 7;
            int e = 16 + ((b << 7) + r) * 8;
            float4 bx = *(const float4*)(wf + e);   // x1, y1, bin_w, bin_h
            int k = wi[e + 4];
            float x1 = bx.x, y1 = bx.y, bw = bx.z, bh = bx.w;

            // ---- y metadata (once per 28 outputs)
            float ys0 = fmaf((float)(2 * ph) + 0.5f, bh, y1);
            float ys1 = ys0 + bh;
            float my0 = (ys0 >= -1.0f && ys0 <= 64.0f) ? 1.0f : 0.0f;
            float my1 = (ys1 >= -1.0f && ys1 <= 64.0f) ? 1.0f : 0.0f;
            float yc0 = fminf(fmaxf(ys0, 0.0f), 63.0f);
            float yc1 = fminf(fmaxf(ys1, 0.0f), 63.0f);
            int y00 = min((int)yc0, 62), y01 = min((int)yc1, 62);
            float ly0 = yc0 - (float)y00, ly1 = yc1 - (float)y01;
            float h0 = (1.0f - ly0) * my0, l0 = ly0 * my0;
            float h1 = (1.0f - ly1) * my1, l1 = ly1 * my1;
            bool dy = (y01 != y00);
            float yw0 = h0 + (dy ? 0.0f : h1);
            float yw1 = l0 + (dy ? h1 : l1);
            float yw2 = dy ? l1 : 0.0f;            // ==0 whenever y00==62
            int  yb = min(y00, 61);
            bool oy = (y00 != yb);
            float yv0 = oy ? 0.0f : yw0;
            float yv1 = oy ? yw0 : yw1;
            float yv2 = oy ? yw1 : yw2;

            float* pout = out + ((size_t)k * 4096 + (c * 16 + tset * 4)) * 49 + ph * 7;
            for (int pw = 0; pw < 7; ++pw) {
                // ---- x metadata (once per 4 outputs); mask + 1/4 folded
                float xs0 = fmaf((float)(2 * pw) + 0.5f, bw, x1);
                float xs1 = xs0 + bw;
                float mx0 = (xs0 >= -1.0f && xs0 <= 64.0f) ? 0.25f : 0.0f;
                float mx1 = (xs1 >= -1.0f && xs1 <= 64.0f) ? 0.25f : 0.0f;
                float xc0 = fminf(fmaxf(xs0, 0.0f), 63.0f);
                float xc1 = fminf(fmaxf(xs1, 0.0f), 63.0f);
                int x00 = min((int)xc0, 62), x01 = min((int)xc1, 62);
                float lx0 = xc0 - (float)x00, lx1 = xc1 - (float)x01;
                float a0 = (1.0f - lx0) * mx0, b0 = lx0 * mx0;
                float a1 = (1.0f - lx1) * mx1, b1 = lx1 * mx1;
                bool dx = (x01 != x00);
                float xw0 = a0 + (dx ? 0.0f : a1);
                float xw1 = b0 + (dx ? a1 : b1);
                float xw2 = dx ? b1 : 0.0f;        // ==0 whenever x00==62
                int  xb = min(x00, 61);
                bool ox = (x00 != xb);
                float xv0 = ox ? 0.0f : xw0;
                float xv1 = ox ? xw0 : xw1;
                float xv2 = ox ? xw1 : xw2;

                const v4f* prow = lds4 + yb * 64 + xb;
                v4f s0 = prow[0]   * xv0 + prow[1]   * xv1 + prow[2]   * xv2;
                v4f s1 = prow[64]  * xv0 + prow[65]  * xv1 + prow[66]  * xv2;
                v4f s2 = prow[128] * xv0 + prow[129] * xv1 + prow[130] * xv2;
                v4f acc = s0 * yv0 + s1 * yv1 + s2 * yv2;

                float* po = pout + pw;
                po[0]   = acc.x;
                po[49]  = acc.y;
                po[98]  = acc.z;
                po[147] = acc.w;
            }
        }
    }
}

extern "C" void kernel_launch(void* const* d_in, const int* in_sizes, int n_in,
                              void* d_out, int out_size, void* d_ws, size_t ws_size,
                              hipStream_t stream) {
    const float* x    = (const float*)d_in[0];
    const float* rois = (const float*)d_in[1];
    float* out = (float*)d_out;
    float* wf  = (float*)d_ws;
    int*   wi  = (int*)d_ws;
    pooler_pre<<<1, 128, 0, stream>>>(rois, wf, wi);
    pooler_main<<<2 * 256, 512, 0, stream>>>(x, wf, wi, out);
}